// Round 5
// baseline (355.001 us; speedup 1.0000x reference)
//
#include <hip/hip_runtime.h>

#define B_ 4096
#define T_ 32
#define A_ 4
#define OBS_ 115
#define H_ 64
#define IN_DIM_ 99
#define ACT_ 19
#define NBT (B_*T_)

typedef _Float16 f16;
typedef _Float16 f16x8 __attribute__((ext_vector_type(8)));
typedef float f32x4 __attribute__((ext_vector_type(4)));

static __device__ __forceinline__ float sigmoid_f(float x) {
    return __builtin_amdgcn_rcpf(1.f + __expf(-x));
}
static __device__ __forceinline__ float tanh_f(float x) {
    return 1.f - 2.f * __builtin_amdgcn_rcpf(1.f + __expf(2.f * x));
}
static __device__ __forceinline__ f32x4 mfma16(f16x8 a, f16x8 b, f32x4 c) {
    return __builtin_amdgcn_mfma_f32_16x16x32_f16(a, b, c, 0, 0, 0);
}
// x += dpp(x); bound_ctrl=1 -> out-of-row src reads 0 (prefix-sum style)
template <int CTRL, int RM>
static __device__ __forceinline__ float dpp_add(float x) {
    int y = __builtin_amdgcn_update_dpp(0, __float_as_int(x), CTRL, RM, 0xf, true);
    return x + __int_as_float(y);
}
// broadcast lane 15 of each 16-lane group (BitMode: and=0x10 or=0x0F xor=0)
static __device__ __forceinline__ float bcast_q15(float x) {
    return __int_as_float(__builtin_amdgcn_ds_swizzle(__float_as_int(x), 0x1F0));
}

// ---- ONE fused kernel: features -> proj+LN (MFMA) -> 2-layer GRU -> cls ----
// Grid 256 x 512 thr. Block owns batch rows [16*blk, 16*blk+16) for all T.
// Barrier plan: stage(wtl/pjw16/hbuf) -> SYNC -> per-wave fused A+B (flh/al are
// wave-local!) -> SYNC -> GRU steps (SYNC each) -> classifier.
// LDS: flh 32768 + pjw16 4096 + al 2048 + wtl 25740 + xls 73728 + hbuf 9216
//    = 147596 B (1 block/CU).
__global__ __launch_bounds__(512, 1) void fused_all(
        const float* __restrict__ obs, const int* __restrict__ act,
        const float* __restrict__ projW, const float* __restrict__ pb,
        const float* __restrict__ lng, const float* __restrict__ lnb,
        const float* __restrict__ Wih0, const float* __restrict__ Whh0,
        const float* __restrict__ bih0, const float* __restrict__ bhh0,
        const float* __restrict__ Wih1, const float* __restrict__ Whh1,
        const float* __restrict__ bih1, const float* __restrict__ bhh1,
        const float* __restrict__ W1, const float* __restrict__ b1,
        const float* __restrict__ W2, const float* __restrict__ b2,
        float* __restrict__ out) {
    __shared__ float wtl[IN_DIM_ * 65];                  // proj_W^T f32 (one-hot rows)
    __shared__ __align__(16) f16 flh[512 * 32];          // feat rows, K-padded 23->32
    __shared__ __align__(16) f16 pjw16[64 * 32];         // proj_W dense part f16
    __shared__ int al[512];                              // 4 actions packed / bt
    __shared__ __align__(16) f16 xls[32 * 16 * 72];      // x[t][row][h], pad 72
    __shared__ __align__(16) f16 hbuf[2][2][16 * 72];    // [layer][pp][row*72+c]

    int tid = threadIdx.x;
    int lane = tid & 63;
    int wv = __builtin_amdgcn_readfirstlane(tid >> 6);   // 0..7
    int c = lane & 15, q = lane >> 4;
    int rowbase = blockIdx.x * 16;

    // ---- 0) issue scattered obs/act loads first; latency hides under staging
    int n = blockIdx.x * 512 + tid;                      // global bt (t fastest, 32/b)
    const float* o = obs + (size_t)n * (A_ * OBS_);
    float2 pA = *(const float2*)&o[0 * OBS_];
    float2 pB = *(const float2*)&o[1 * OBS_];
    float2 pC = *(const float2*)&o[2 * OBS_];
    float2 pD = *(const float2*)&o[3 * OBS_];
    float2 bl = *(const float2*)&o[88];
    int4 av = *(const int4*)&act[n * A_];

    // ---- 1) stage proj weights + zero hbuf (the only cross-wave A-data) ----
    for (int k = tid; k < IN_DIM_ * 64; k += 512) {      // wtl stride 65 bank-clean
        int hh = k / IN_DIM_, ii = k - hh * IN_DIM_;
        wtl[ii * 65 + hh] = projW[k];
    }
    for (int k = tid; k < 64 * 32; k += 512) {           // dense part as f16 B-rows
        int h = k >> 5, kk = k & 31;
        pjw16[k] = (kk < 23) ? (f16)projW[h * IN_DIM_ + kk] : (f16)0.f;
    }
    for (int k = tid; k < 2 * 2 * 16 * 72 / 2; k += 512) ((unsigned*)hbuf)[k] = 0u;
    __syncthreads();

    // ---- 2) features -> flh + al (consumed only by THIS wave: no barrier) ----
    {
        float px[A_], py[A_];
        px[0] = pA.x; py[0] = pA.y; px[1] = pB.x; py[1] = pB.y;
        px[2] = pC.x; py[2] = pC.y; px[3] = pD.x; py[3] = pD.y;
        // prev-t ball lives in the previous lane of this 32-lane segment
        float pblx = __shfl_up(bl.x, 1, 32);             // lane t=0 gets own -> vel 0
        float pbly = __shfl_up(bl.y, 1, 32);

        float cx = (px[0] + px[1] + px[2] + px[3]) * 0.25f;
        float cy = (py[0] + py[1] + py[2] + py[3]) * 0.25f;
        float sp = 0.f;
#pragma unroll
        for (int a = 0; a < A_; a++) { float dx = px[a] - cx, dy = py[a] - cy; sp += dx * dx + dy * dy; }
        sp = sqrtf(sp * 0.25f + 1e-6f);

        float fr[23];
        fr[0] = bl.x; fr[1] = bl.y; fr[2] = bl.x - pblx; fr[3] = bl.y - pbly;
#pragma unroll
        for (int a = 0; a < A_; a++) { fr[4 + 2 * a] = px[a]; fr[5 + 2 * a] = py[a]; }
        fr[12] = cx; fr[13] = cy; fr[14] = sp;
#pragma unroll
        for (int i = 0; i < A_; i++) {
            float best = 3.4e38f; int bj = 0;
#pragma unroll
            for (int j = 0; j < A_; j++) {
                if (j == i) continue;
                float dx = px[i] - px[j], dy = py[i] - py[j];
                float d2 = dx * dx + dy * dy;
                if (d2 < best) { best = d2; bj = j; }
            }
            fr[15 + 2 * i] = px[bj] - px[i]; fr[16 + 2 * i] = py[bj] - py[i];
        }

        al[tid] = av.x | (av.y << 8) | (av.z << 16) | (av.w << 24);

        // pack features into the f16 A-row (cols 23..31 = 0)
        f16x8 p0, p1, p2, p3 = {};
#pragma unroll
        for (int i = 0; i < 8; i++) { p0[i] = (f16)fr[i]; p1[i] = (f16)fr[8 + i]; }
#pragma unroll
        for (int i = 0; i < 7; i++) p2[i] = (f16)fr[16 + i];
        p2[7] = (f16)0.f;
        *(f16x8*)&flh[tid * 32]      = p0;
        *(f16x8*)&flh[tid * 32 + 8]  = p1;
        *(f16x8*)&flh[tid * 32 + 16] = p2;
        *(f16x8*)&flh[tid * 32 + 24] = p3;
    }

    // ---- 3) GRU weight preamble: issued here so HBM latency hides under B ----
    auto ldw = [&](const float* W, int row0, int kcol) -> f16x8 {
        const float* p = W + (size_t)(row0 + c) * 64 + kcol + q * 8;
        f32x4 w0 = *(const f32x4*)p;
        f32x4 w1 = *(const f32x4*)(p + 4);
        f16x8 r;
        r[0] = (f16)w0[0]; r[1] = (f16)w0[1]; r[2] = (f16)w0[2]; r[3] = (f16)w0[3];
        r[4] = (f16)w1[0]; r[5] = (f16)w1[1]; r[6] = (f16)w1[2]; r[7] = (f16)w1[3];
        return r;
    };
    int L = wv >> 2;                                     // GRU layer this wave owns
    int S = (wv & 3) * 16;                               // hidden strip
    const float* Wih = L ? Wih1 : Wih0;
    const float* Whh = L ? Whh1 : Whh0;
    const float* bih = L ? bih1 : bih0;
    const float* bhh = L ? bhh1 : bhh0;
    f16x8 wih[3][2], whh[3][2];
#pragma unroll
    for (int g = 0; g < 3; g++)
#pragma unroll
        for (int kf = 0; kf < 2; kf++) {
            wih[g][kf] = ldw(Wih, g * 64 + S, kf * 32);
            whh[g][kf] = ldw(Whh, g * 64 + S, kf * 32);
        }
    float br = bih[S + c] + bhh[S + c];                  // r-gate bias (h-side chain)
    float bz = bih[64 + S + c] + bhh[64 + S + c];        // z-gate bias (h-side chain)
    float bi = bih[128 + S + c];                         // n-gate x-side bias
    float bh = bhh[128 + S + c];                         // n-gate h-side bias
    f32x4 vbr = {br, br, br, br}, vbz = {bz, bz, bz, bz};
    f32x4 vbi = {bi, bi, bi, bi}, vbh = {bh, bh, bh, bh};
    f32x4 z4 = {0.f, 0.f, 0.f, 0.f};

    // ---- 4) Phase B: proj via MFMA + one-hot gather + LN (DPP) + ReLU ----
    {
        float pbv[4], gg[4], bbv[4];
        f16x8 bfr[4];
#pragma unroll
        for (int tl = 0; tl < 4; tl++) {
            int col = tl * 16 + c;
            pbv[tl] = pb[col]; gg[tl] = lng[col]; bbv[tl] = lnb[col];
            bfr[tl] = *(const f16x8*)&pjw16[col * 32 + q * 8];
        }
#pragma unroll
        for (int rt = 0; rt < 4; rt++) {
            int row0 = wv * 64 + rt * 16;                // local bt tile base
            f16x8 af = *(const f16x8*)&flh[(row0 + c) * 32 + q * 8];
            f32x4 a0 = mfma16(af, bfr[0], z4);
            f32x4 a1 = mfma16(af, bfr[1], z4);
            f32x4 a2 = mfma16(af, bfr[2], z4);
            f32x4 a3 = mfma16(af, bfr[3], z4);
#pragma unroll
            for (int rr = 0; rr < 4; rr++) {
                int lb = row0 + q * 4 + rr;              // this lane's bt row
                int a4i = al[lb];
                float v0 = a0[rr] + pbv[0];
                float v1 = a1[rr] + pbv[1];
                float v2 = a2[rr] + pbv[2];
                float v3 = a3[rr] + pbv[3];
#pragma unroll
                for (int a = 0; a < 4; a++) {
                    const float* wrow =
                        &wtl[(23 + a * ACT_ + ((a4i >> (8 * a)) & 0xFF)) * 65 + c];
                    v0 += wrow[0]; v1 += wrow[16]; v2 += wrow[32]; v3 += wrow[48];
                }
                // 16-lane (same-q) sum via DPP prefix adds; total lands in lane 15
                float s = (v0 + v1) + (v2 + v3);
                float ss = v0 * v0 + v1 * v1 + v2 * v2 + v3 * v3;
                s = dpp_add<0x111, 0xf>(s);  ss = dpp_add<0x111, 0xf>(ss);  // shr 1
                s = dpp_add<0x112, 0xf>(s);  ss = dpp_add<0x112, 0xf>(ss);  // shr 2
                s = dpp_add<0x114, 0xf>(s);  ss = dpp_add<0x114, 0xf>(ss);  // shr 4
                s = dpp_add<0x118, 0xf>(s);  ss = dpp_add<0x118, 0xf>(ss);  // shr 8
                float stot = bcast_q15(s), sstot = bcast_q15(ss);
                float mean = stot * (1.f / 64.f);
                float var = sstot * (1.f / 64.f) - mean * mean;
                float rs = rsqrtf(var + 1e-5f);
                int t = lb & 31, r = lb >> 5;
                f16* xrow = &xls[(t * 16 + r) * 72];
                float xn;
                xn = fmaxf((v0 - mean) * rs * gg[0] + bbv[0], 0.f); xrow[c]      = (f16)xn;
                xn = fmaxf((v1 - mean) * rs * gg[1] + bbv[1], 0.f); xrow[16 + c] = (f16)xn;
                xn = fmaxf((v2 - mean) * rs * gg[2] + bbv[2], 0.f); xrow[32 + c] = (f16)xn;
                xn = fmaxf((v3 - mean) * rs * gg[3] + bbv[3], 0.f); xrow[48 + c] = (f16)xn;
            }
        }
    }
    __syncthreads();

    // ---- 5) Phase C: layer-split GRU; 2-deep MFMA chains; first-step skip ----
    f32x4 hc = {0.f, 0.f, 0.f, 0.f};
    int p = 0;
    f16x8 in0, in1;
    if (L == 0) {                                        // preload t=0 input (static)
        in0 = *(const f16x8*)&xls[(0 * 16 + c) * 72 + q * 8];
        in1 = *(const f16x8*)&xls[(0 * 16 + c) * 72 + 32 + q * 8];
    }
    for (int i = 0; i <= T_; i++) {
        bool active = L ? (i > 0) : (i < T_);
        bool first  = L ? (i == 1) : (i == 0);
        if (L == 1 && active) {                          // L1 input = L0's h
            in0 = *(const f16x8*)&hbuf[0][p][c * 72 + q * 8];
            in1 = *(const f16x8*)&hbuf[0][p][c * 72 + 32 + q * 8];
        }
        if (active) {
            // x-side chains (in-frags already in regs)
            f32x4 gir = mfma16(in0, wih[0][0], z4);
            f32x4 giz = mfma16(in0, wih[1][0], z4);
            f32x4 gin = mfma16(in0, wih[2][0], vbi);
            gir = mfma16(in1, wih[0][1], gir);
            giz = mfma16(in1, wih[1][1], giz);
            gin = mfma16(in1, wih[2][1], gin);
            // h-side chains; h == 0 at first active step -> biases only
            f32x4 ghr, ghz, ghn;
            if (!first) {
                f16x8 hh0 = *(const f16x8*)&hbuf[L][p][c * 72 + q * 8];
                f16x8 hh1 = *(const f16x8*)&hbuf[L][p][c * 72 + 32 + q * 8];
                ghr = mfma16(hh0, whh[0][0], vbr);
                ghz = mfma16(hh0, whh[1][0], vbz);
                ghn = mfma16(hh0, whh[2][0], vbh);
                ghr = mfma16(hh1, whh[0][1], ghr);
                ghz = mfma16(hh1, whh[1][1], ghz);
                ghn = mfma16(hh1, whh[2][1], ghn);
            } else { ghr = vbr; ghz = vbz; ghn = vbh; }
            // prefetch next-t input for L0 while MFMAs drain (xls is static)
            if (L == 0) {
                int tn = (i + 1 < T_) ? (i + 1) : (T_ - 1);
                in0 = *(const f16x8*)&xls[(tn * 16 + c) * 72 + q * 8];
                in1 = *(const f16x8*)&xls[(tn * 16 + c) * 72 + 32 + q * 8];
            }
#pragma unroll
            for (int rr = 0; rr < 4; rr++) {
                float rg = sigmoid_f(gir[rr] + ghr[rr]);
                float zg = sigmoid_f(giz[rr] + ghz[rr]);
                float ng = tanh_f(gin[rr] + rg * ghn[rr]);
                hc[rr] = ng + zg * (hc[rr] - ng);
            }
#pragma unroll
            for (int rr = 0; rr < 4; rr++)
                hbuf[L][p ^ 1][(q * 4 + rr) * 72 + S + c] = (f16)hc[rr];
        }
        __syncthreads();
        p ^= 1;
    }

    // ---- classifier ----
    f16x8 ha0 = *(const f16x8*)&hbuf[1][p][c * 72 + q * 8];
    f16x8 ha1 = *(const f16x8*)&hbuf[1][p][c * 72 + 32 + q * 8];
    if (L == 0) {
        f16x8 w1f0 = ldw(W1, S, 0), w1f1 = ldw(W1, S, 32);
        float bw1 = b1[S + c];
        f32x4 hid = {bw1, bw1, bw1, bw1};
        hid = mfma16(ha0, w1f0, hid);
        hid = mfma16(ha1, w1f1, hid);
#pragma unroll
        for (int rr = 0; rr < 4; rr++) {
            float hv = fmaxf(hid[rr], 0.f);
            hbuf[0][p ^ 1][(q * 4 + rr) * 72 + S + c] = (f16)hv;
        }
    }
    __syncthreads();
    if (wv == 0) {
        f16x8 ga0 = *(const f16x8*)&hbuf[0][p ^ 1][c * 72 + q * 8];
        f16x8 ga1 = *(const f16x8*)&hbuf[0][p ^ 1][c * 72 + 32 + q * 8];
        f16x8 w2f0 = {}, w2f1 = {};
        float bo = 0.f;
        if (c < 8) {
            w2f0 = ldw(W2, 0, 0);
            w2f1 = ldw(W2, 0, 32);
            bo = b2[c];
        }
        f32x4 lg = {bo, bo, bo, bo};
        lg = mfma16(ga0, w2f0, lg);
        lg = mfma16(ga1, w2f1, lg);
        if (c < 8) {
#pragma unroll
            for (int rr = 0; rr < 4; rr++)
                out[(size_t)(rowbase + q * 4 + rr) * 8 + c] = lg[rr];
        }
    }
}

extern "C" void kernel_launch(void* const* d_in, const int* in_sizes, int n_in,
                              void* d_out, int out_size, void* d_ws, size_t ws_size,
                              hipStream_t stream) {
    const float* obs  = (const float*)d_in[0];
    const int*   act  = (const int*)d_in[1];
    const float* projW = (const float*)d_in[2];
    const float* projb = (const float*)d_in[3];
    const float* lng  = (const float*)d_in[4];
    const float* lnb  = (const float*)d_in[5];
    const float* Wih0 = (const float*)d_in[6];
    const float* Whh0 = (const float*)d_in[7];
    const float* bih0 = (const float*)d_in[8];
    const float* bhh0 = (const float*)d_in[9];
    const float* Wih1 = (const float*)d_in[10];
    const float* Whh1 = (const float*)d_in[11];
    const float* bih1 = (const float*)d_in[12];
    const float* bhh1 = (const float*)d_in[13];
    const float* W1   = (const float*)d_in[14];
    const float* b1   = (const float*)d_in[15];
    const float* W2   = (const float*)d_in[16];
    const float* b2   = (const float*)d_in[17];
    float* out = (float*)d_out;

    fused_all<<<B_ / 16, 512, 0, stream>>>(obs, act, projW, projb, lng, lnb,
                                           Wih0, Whh0, bih0, bhh0,
                                           Wih1, Whh1, bih1, bhh1,
                                           W1, b1, W2, b2, out);
}

// Round 6
// 347.279 us; speedup vs baseline: 1.0222x; 1.0222x over previous
//
#include <hip/hip_runtime.h>

#define B_ 4096
#define T_ 32
#define A_ 4
#define OBS_ 115
#define H_ 64
#define IN_DIM_ 99
#define ACT_ 19
#define NBT (B_*T_)

typedef _Float16 f16;
typedef _Float16 f16x8 __attribute__((ext_vector_type(8)));
typedef float f32x4 __attribute__((ext_vector_type(4)));

static __device__ __forceinline__ float sigmoid_f(float x) {
    return __builtin_amdgcn_rcpf(1.f + __expf(-x));
}
static __device__ __forceinline__ float tanh_f(float x) {
    return 1.f - 2.f * __builtin_amdgcn_rcpf(1.f + __expf(2.f * x));
}
static __device__ __forceinline__ f32x4 mfma16(f16x8 a, f16x8 b, f32x4 c) {
    return __builtin_amdgcn_mfma_f32_16x16x32_f16(a, b, c, 0, 0, 0);
}
// x += dpp(x); bound_ctrl=1 -> out-of-row src reads 0 (prefix-sum style)
template <int CTRL, int RM>
static __device__ __forceinline__ float dpp_add(float x) {
    int y = __builtin_amdgcn_update_dpp(0, __float_as_int(x), CTRL, RM, 0xf, true);
    return x + __int_as_float(y);
}
// broadcast lane 15 of each 16-lane group (BitMode: and=0x10 or=0x0F xor=0)
static __device__ __forceinline__ float bcast_q15(float x) {
    return __int_as_float(__builtin_amdgcn_ds_swizzle(__float_as_int(x), 0x1F0));
}

// ---- ONE fused kernel: features -> proj+LN (MFMA) -> 2-layer GRU -> cls ----
// Grid 256 x 512 thr. Block owns batch rows [16*blk, 16*blk+16) for all T.
// R6 = R4 structure + one-hot gather as interleaved-chunk f32x4 rows:
//   ohw[row*64 + c*4 + tl] = projW_T[row][tl*16+c]  ->  one ds_read_b128/action.
// LDS: ohw 19456 + flh 32768 + pjw16 4096 + al 2048 + xls 73728 + hbuf 9216
//    = 141312 B (1 block/CU).
__global__ __launch_bounds__(512, 1) void fused_all(
        const float* __restrict__ obs, const int* __restrict__ act,
        const float* __restrict__ projW, const float* __restrict__ pb,
        const float* __restrict__ lng, const float* __restrict__ lnb,
        const float* __restrict__ Wih0, const float* __restrict__ Whh0,
        const float* __restrict__ bih0, const float* __restrict__ bhh0,
        const float* __restrict__ Wih1, const float* __restrict__ Whh1,
        const float* __restrict__ bih1, const float* __restrict__ bhh1,
        const float* __restrict__ W1, const float* __restrict__ b1,
        const float* __restrict__ W2, const float* __restrict__ b2,
        float* __restrict__ out) {
    __shared__ __align__(16) float ohw[76 * 64];         // one-hot rows, chunk-interleaved
    __shared__ __align__(16) f16 flh[512 * 32];          // feat rows, K-padded 23->32
    __shared__ __align__(16) f16 pjw16[64 * 32];         // proj_W dense part f16
    __shared__ int al[512];                              // 4 actions packed / bt
    __shared__ __align__(16) f16 xls[32 * 16 * 72];      // x[t][row][h], pad 72
    __shared__ __align__(16) f16 hbuf[2][2][16 * 72];    // [layer][pp][row*72+c]

    int tid = threadIdx.x;
    int lane = tid & 63;
    int wv = __builtin_amdgcn_readfirstlane(tid >> 6);   // 0..7
    int c = lane & 15, q = lane >> 4;
    int rowbase = blockIdx.x * 16;

    // ---- GRU weight preamble (cold HBM latency hides under phase A/B) ----
    auto ldw = [&](const float* W, int row0, int kcol) -> f16x8 {
        const float* p = W + (size_t)(row0 + c) * 64 + kcol + q * 8;
        f32x4 w0 = *(const f32x4*)p;
        f32x4 w1 = *(const f32x4*)(p + 4);
        f16x8 r;
        r[0] = (f16)w0[0]; r[1] = (f16)w0[1]; r[2] = (f16)w0[2]; r[3] = (f16)w0[3];
        r[4] = (f16)w1[0]; r[5] = (f16)w1[1]; r[6] = (f16)w1[2]; r[7] = (f16)w1[3];
        return r;
    };
    int L = wv >> 2;                                     // GRU layer this wave owns
    int S = (wv & 3) * 16;                               // hidden strip
    const float* Wih = L ? Wih1 : Wih0;
    const float* Whh = L ? Whh1 : Whh0;
    const float* bih = L ? bih1 : bih0;
    const float* bhh = L ? bhh1 : bhh0;
    f16x8 wih[3][2], whh[3][2];
#pragma unroll
    for (int g = 0; g < 3; g++)
#pragma unroll
        for (int kf = 0; kf < 2; kf++) {
            wih[g][kf] = ldw(Wih, g * 64 + S, kf * 32);
            whh[g][kf] = ldw(Whh, g * 64 + S, kf * 32);
        }
    float br = bih[S + c] + bhh[S + c];                  // r-gate bias (h-side chain)
    float bz = bih[64 + S + c] + bhh[64 + S + c];        // z-gate bias (h-side chain)
    float bi = bih[128 + S + c];                         // n-gate x-side bias
    float bh = bhh[128 + S + c];                         // n-gate h-side bias
    f32x4 vbr = {br, br, br, br}, vbz = {bz, bz, bz, bz};
    f32x4 vbi = {bi, bi, bi, bi}, vbh = {bh, bh, bh, bh};
    f32x4 z4 = {0.f, 0.f, 0.f, 0.f};

    // ---- Phase A: feature extraction -> flh (f16 A-rows) + al + staging ----
    {
        int n = blockIdx.x * 512 + tid;                  // global bt (t fastest, 32/b)
        const float* o = obs + (size_t)n * (A_ * OBS_);
        float px[A_], py[A_];
#pragma unroll
        for (int a = 0; a < A_; a++) {
            float2 p2 = *(const float2*)&o[a * OBS_];
            px[a] = p2.x; py[a] = p2.y;
        }
        float2 bl = *(const float2*)&o[88];
        // prev-t ball lives in the previous lane of this 32-lane segment
        float pblx = __shfl_up(bl.x, 1, 32);             // lane t=0 gets own -> vel 0
        float pbly = __shfl_up(bl.y, 1, 32);

        float cx = (px[0] + px[1] + px[2] + px[3]) * 0.25f;
        float cy = (py[0] + py[1] + py[2] + py[3]) * 0.25f;
        float sp = 0.f;
#pragma unroll
        for (int a = 0; a < A_; a++) { float dx = px[a] - cx, dy = py[a] - cy; sp += dx * dx + dy * dy; }
        sp = sqrtf(sp * 0.25f + 1e-6f);

        float fr[23];
        fr[0] = bl.x; fr[1] = bl.y; fr[2] = bl.x - pblx; fr[3] = bl.y - pbly;
#pragma unroll
        for (int a = 0; a < A_; a++) { fr[4 + 2 * a] = px[a]; fr[5 + 2 * a] = py[a]; }
        fr[12] = cx; fr[13] = cy; fr[14] = sp;
#pragma unroll
        for (int i = 0; i < A_; i++) {
            float best = 3.4e38f; int bj = 0;
#pragma unroll
            for (int j = 0; j < A_; j++) {
                if (j == i) continue;
                float dx = px[i] - px[j], dy = py[i] - py[j];
                float d2 = dx * dx + dy * dy;
                if (d2 < best) { best = d2; bj = j; }
            }
            fr[15 + 2 * i] = px[bj] - px[i]; fr[16 + 2 * i] = py[bj] - py[i];
        }

        int4 av = *(const int4*)&act[n * A_];
        al[tid] = av.x | (av.y << 8) | (av.z << 16) | (av.w << 24);

        // pack features into the f16 A-row (cols 23..31 = 0)
        f16x8 p0, p1, p2, p3 = {};
#pragma unroll
        for (int i = 0; i < 8; i++) { p0[i] = (f16)fr[i]; p1[i] = (f16)fr[8 + i]; }
#pragma unroll
        for (int i = 0; i < 7; i++) p2[i] = (f16)fr[16 + i];
        p2[7] = (f16)0.f;
        *(f16x8*)&flh[tid * 32]      = p0;
        *(f16x8*)&flh[tid * 32 + 8]  = p1;
        *(f16x8*)&flh[tid * 32 + 16] = p2;
        *(f16x8*)&flh[tid * 32 + 24] = p3;

        // stage one-hot rows chunk-interleaved: ohw[i*64 + cc*4 + ch] =
        // projW[(ch*16+cc)*99 + 23+i]. Consecutive k -> consecutive LDS addr
        // (bank-clean writes); projW reads land in L2/L3 (25 KB, shared).
        for (int k = tid; k < 76 * 64; k += 512) {
            int i = k >> 6, low = k & 63;
            int cc = low >> 2, ch = low & 3;
            ohw[k] = projW[(ch * 16 + cc) * IN_DIM_ + 23 + i];
        }
        // dense proj weights as f16 B-rows: pjw16[h][k], k 23..31 = 0
        for (int k = tid; k < 64 * 32; k += 512) {
            int h = k >> 5, kk = k & 31;
            pjw16[k] = (kk < 23) ? (f16)projW[h * IN_DIM_ + kk] : (f16)0.f;
        }
        for (int k = tid; k < 2 * 2 * 16 * 72; k += 512) ((f16*)hbuf)[k] = (f16)0.f;
    }
    __syncthreads();

    // ---- Phase B: proj via MFMA + one-hot b128 gather + LN (DPP) + ReLU ----
    {
        float pbv[4], gg[4], bbv[4];
        f16x8 bfr[4];
#pragma unroll
        for (int tl = 0; tl < 4; tl++) {
            int col = tl * 16 + c;
            pbv[tl] = pb[col]; gg[tl] = lng[col]; bbv[tl] = lnb[col];
            bfr[tl] = *(const f16x8*)&pjw16[col * 32 + q * 8];
        }
#pragma unroll
        for (int rt = 0; rt < 4; rt++) {
            int row0 = wv * 64 + rt * 16;                // local bt tile base
            f16x8 af = *(const f16x8*)&flh[(row0 + c) * 32 + q * 8];
            f32x4 a0 = mfma16(af, bfr[0], z4);
            f32x4 a1 = mfma16(af, bfr[1], z4);
            f32x4 a2 = mfma16(af, bfr[2], z4);
            f32x4 a3 = mfma16(af, bfr[3], z4);
#pragma unroll
            for (int rr = 0; rr < 4; rr++) {
                int lb = row0 + q * 4 + rr;              // this lane's bt row
                int a4i = al[lb];
                float v0 = a0[rr] + pbv[0];
                float v1 = a1[rr] + pbv[1];
                float v2 = a2[rr] + pbv[2];
                float v3 = a3[rr] + pbv[3];
#pragma unroll
                for (int a = 0; a < 4; a++) {
                    int ai = (a4i >> (8 * a)) & 0xFF;
                    f32x4 w4 = *(const f32x4*)&ohw[(a * ACT_ + ai) * 64 + c * 4];
                    v0 += w4[0]; v1 += w4[1]; v2 += w4[2]; v3 += w4[3];
                }
                // 16-lane (same-q) sum via DPP prefix adds; total lands in lane 15
                float s = (v0 + v1) + (v2 + v3);
                float ss = v0 * v0 + v1 * v1 + v2 * v2 + v3 * v3;
                s = dpp_add<0x111, 0xf>(s);  ss = dpp_add<0x111, 0xf>(ss);  // shr 1
                s = dpp_add<0x112, 0xf>(s);  ss = dpp_add<0x112, 0xf>(ss);  // shr 2
                s = dpp_add<0x114, 0xf>(s);  ss = dpp_add<0x114, 0xf>(ss);  // shr 4
                s = dpp_add<0x118, 0xf>(s);  ss = dpp_add<0x118, 0xf>(ss);  // shr 8
                float stot = bcast_q15(s), sstot = bcast_q15(ss);
                float mean = stot * (1.f / 64.f);
                float var = sstot * (1.f / 64.f) - mean * mean;
                float rs = rsqrtf(var + 1e-5f);
                int t = lb & 31, r = lb >> 5;
                f16* xrow = &xls[(t * 16 + r) * 72];
                float xn;
                xn = fmaxf((v0 - mean) * rs * gg[0] + bbv[0], 0.f); xrow[c]      = (f16)xn;
                xn = fmaxf((v1 - mean) * rs * gg[1] + bbv[1], 0.f); xrow[16 + c] = (f16)xn;
                xn = fmaxf((v2 - mean) * rs * gg[2] + bbv[2], 0.f); xrow[32 + c] = (f16)xn;
                xn = fmaxf((v3 - mean) * rs * gg[3] + bbv[3], 0.f); xrow[48 + c] = (f16)xn;
            }
        }
    }
    __syncthreads();

    // ---- Phase C: layer-split GRU; gi/gh split into 2-deep MFMA chains ----
    f32x4 hc = {0.f, 0.f, 0.f, 0.f};
    int p = 0;
    f16x8 in0, in1;
    if (L == 0) {                                        // preload t=0 input (static)
        in0 = *(const f16x8*)&xls[(0 * 16 + c) * 72 + q * 8];
        in1 = *(const f16x8*)&xls[(0 * 16 + c) * 72 + 32 + q * 8];
    }
    for (int i = 0; i <= T_; i++) {
        f16x8 hh0 = *(const f16x8*)&hbuf[L][p][c * 72 + q * 8];
        f16x8 hh1 = *(const f16x8*)&hbuf[L][p][c * 72 + 32 + q * 8];
        if (L == 1) {                                    // L1 input = L0's h (same barrier)
            in0 = *(const f16x8*)&hbuf[0][p][c * 72 + q * 8];
            in1 = *(const f16x8*)&hbuf[0][p][c * 72 + 32 + q * 8];
        }
        bool active = L ? (i > 0) : (i < T_);
        if (active) {
            // x-side chains (independent of h; in-frags already in regs for L0)
            f32x4 gir = mfma16(in0, wih[0][0], z4);
            f32x4 giz = mfma16(in0, wih[1][0], z4);
            f32x4 gin = mfma16(in0, wih[2][0], vbi);
            gir = mfma16(in1, wih[0][1], gir);
            giz = mfma16(in1, wih[1][1], giz);
            gin = mfma16(in1, wih[2][1], gin);
            // h-side chains
            f32x4 ghr = mfma16(hh0, whh[0][0], vbr);
            f32x4 ghz = mfma16(hh0, whh[1][0], vbz);
            f32x4 ghn = mfma16(hh0, whh[2][0], vbh);
            ghr = mfma16(hh1, whh[0][1], ghr);
            ghz = mfma16(hh1, whh[1][1], ghz);
            ghn = mfma16(hh1, whh[2][1], ghn);
            // prefetch next-t input for L0 while MFMAs drain (xls is static)
            if (L == 0) {
                int tn = (i + 1 < T_) ? (i + 1) : (T_ - 1);
                in0 = *(const f16x8*)&xls[(tn * 16 + c) * 72 + q * 8];
                in1 = *(const f16x8*)&xls[(tn * 16 + c) * 72 + 32 + q * 8];
            }
#pragma unroll
            for (int rr = 0; rr < 4; rr++) {
                float rg = sigmoid_f(gir[rr] + ghr[rr]);
                float zg = sigmoid_f(giz[rr] + ghz[rr]);
                float ng = tanh_f(gin[rr] + rg * ghn[rr]);
                hc[rr] = ng + zg * (hc[rr] - ng);
            }
        }
#pragma unroll
        for (int rr = 0; rr < 4; rr++)
            hbuf[L][p ^ 1][(q * 4 + rr) * 72 + S + c] = (f16)hc[rr];
        __syncthreads();
        p ^= 1;
    }

    // ---- classifier ----
    f16x8 ha0 = *(const f16x8*)&hbuf[1][p][c * 72 + q * 8];
    f16x8 ha1 = *(const f16x8*)&hbuf[1][p][c * 72 + 32 + q * 8];
    if (L == 0) {
        f16x8 w1f0 = ldw(W1, S, 0), w1f1 = ldw(W1, S, 32);
        float bw1 = b1[S + c];
        f32x4 hid = {bw1, bw1, bw1, bw1};
        hid = mfma16(ha0, w1f0, hid);
        hid = mfma16(ha1, w1f1, hid);
#pragma unroll
        for (int rr = 0; rr < 4; rr++) {
            float hv = fmaxf(hid[rr], 0.f);
            hbuf[0][p ^ 1][(q * 4 + rr) * 72 + S + c] = (f16)hv;
        }
    }
    __syncthreads();
    if (wv == 0) {
        f16x8 ga0 = *(const f16x8*)&hbuf[0][p ^ 1][c * 72 + q * 8];
        f16x8 ga1 = *(const f16x8*)&hbuf[0][p ^ 1][c * 72 + 32 + q * 8];
        f16x8 w2f0 = {}, w2f1 = {};
        float bo = 0.f;
        if (c < 8) {
            w2f0 = ldw(W2, 0, 0);
            w2f1 = ldw(W2, 0, 32);
            bo = b2[c];
        }
        f32x4 lg = {bo, bo, bo, bo};
        lg = mfma16(ga0, w2f0, lg);
        lg = mfma16(ga1, w2f1, lg);
        if (c < 8) {
#pragma unroll
            for (int rr = 0; rr < 4; rr++)
                out[(size_t)(rowbase + q * 4 + rr) * 8 + c] = lg[rr];
        }
    }
}

extern "C" void kernel_launch(void* const* d_in, const int* in_sizes, int n_in,
                              void* d_out, int out_size, void* d_ws, size_t ws_size,
                              hipStream_t stream) {
    const float* obs  = (const float*)d_in[0];
    const int*   act  = (const int*)d_in[1];
    const float* projW = (const float*)d_in[2];
    const float* projb = (const float*)d_in[3];
    const float* lng  = (const float*)d_in[4];
    const float* lnb  = (const float*)d_in[5];
    const float* Wih0 = (const float*)d_in[6];
    const float* Whh0 = (const float*)d_in[7];
    const float* bih0 = (const float*)d_in[8];
    const float* bhh0 = (const float*)d_in[9];
    const float* Wih1 = (const float*)d_in[10];
    const float* Whh1 = (const float*)d_in[11];
    const float* bih1 = (const float*)d_in[12];
    const float* bhh1 = (const float*)d_in[13];
    const float* W1   = (const float*)d_in[14];
    const float* b1   = (const float*)d_in[15];
    const float* W2   = (const float*)d_in[16];
    const float* b2   = (const float*)d_in[17];
    float* out = (float*)d_out;

    fused_all<<<B_ / 16, 512, 0, stream>>>(obs, act, projW, projb, lng, lnb,
                                           Wih0, Whh0, bih0, bhh0,
                                           Wih1, Whh1, bih1, bhh1,
                                           W1, b1, W2, b2, out);
}